// Round 10
// baseline (50.666 us; speedup 1.0000x reference)
//
#include <hip/hip_runtime.h>

// Problem constants (fixed by the reference file): B=8, N=4096.
#define NN 4096
#define BB 8
#define JT 4          // ISNet rows per wave
#define BT 4          // batches per wave
#define KS 2          // k-splits
#define KH (NN / KS)  // 2048 k per wave

// Main kernel: grid NN/JT = 1024 blocks x 256 threads = 4 INDEPENDENT waves.
// Wave w -> (bg = w&1, ks = w>>1): rows j0..j0+3, batches bg*4..bg*4+3,
// k in [ks*KH, (ks+1)*KH). No LDS, no barriers in the main loop (the R7/8/9
// staging experiments all lost to the barrier-free R4/6 shape).
// Register tiling JT x BT = 16 f64 accumulators: chip-wide traffic
// w 512/BT + I 512/JT = 256 MB vs R6's 384 MB, same 4 waves/SIMD.
// Partial products -> d_ws[KS][BB][NN]; combine kernel (verified in R9)
// multiplies halves + 4x4 mix + cumulative-threshold sampling.
// Factor math identical to the R4/6/9 passing scheme.

__device__ __forceinline__ float2 pk_mul(float2 a, float2 b) {
    return make_float2(a.x * b.x, a.y * b.y);
}
__device__ __forceinline__ float2 pk_add(float2 a, float2 b) {
    return make_float2(a.x + b.x, a.y + b.y);
}
__device__ __forceinline__ float2 pk_fnma(float2 a, float2 b, float2 c) {  // c - a*b
    return make_float2(fmaf(-a.x, b.x, c.x), fmaf(-a.y, b.y, c.y));
}

__global__ __launch_bounds__(256, 4) void epi_partial(
    const float* __restrict__ state,    // [B,4,N]
    const float* __restrict__ ISNet,    // [N,N]
    const float* __restrict__ psMatrix, // [4,4]
    double* __restrict__ ws)            // [KS,BB,NN] partial products
{
    const int j0   = blockIdx.x * JT;
    const int tid  = threadIdx.x;
    const int wave = tid >> 6;
    const int lane = tid & 63;
    const int bg   = wave & 1;
    const int ks   = wave >> 1;
    const int b0   = bg * BT;
    const int kb   = ks * KH;

    const float p01 = psMatrix[1];      // psM[0,1] == psMatrix[0,1]

    float  cf[JT][BT];
    double prod[JT][BT];
    #pragma unroll
    for (int jj = 0; jj < JT; ++jj) {
        #pragma unroll
        for (int bi = 0; bi < BT; ++bi) {
            cf[jj][bi]   = state[(size_t)(b0 + bi) * 4 * NN + (j0 + jj)] * p01;
            prod[jj][bi] = 1.0;
        }
    }

    const float4* __restrict__ w4_0 = (const float4*)(ISNet + (size_t)(j0 + 0) * NN + kb);
    const float4* __restrict__ w4_1 = (const float4*)(ISNet + (size_t)(j0 + 1) * NN + kb);
    const float4* __restrict__ w4_2 = (const float4*)(ISNet + (size_t)(j0 + 2) * NN + kb);
    const float4* __restrict__ w4_3 = (const float4*)(ISNet + (size_t)(j0 + 3) * NN + kb);
    const float4* __restrict__ i4_0 = (const float4*)(state + ((size_t)(b0 + 0) * 4 + 2) * NN + kb);
    const float4* __restrict__ i4_1 = (const float4*)(state + ((size_t)(b0 + 1) * 4 + 2) * NN + kb);
    const float4* __restrict__ i4_2 = (const float4*)(state + ((size_t)(b0 + 2) * 4 + 2) * NN + kb);
    const float4* __restrict__ i4_3 = (const float4*)(state + ((size_t)(b0 + 3) * 4 + 2) * NN + kb);

    float4 wA[JT], wB[JT], iA[BT], iB[BT];

#define LD(W, I, IT)                                        \
    do {                                                    \
        const int _x = lane + (IT) * 64;                    \
        W[0] = w4_0[_x]; W[1] = w4_1[_x];                   \
        W[2] = w4_2[_x]; W[3] = w4_3[_x];                   \
        I[0] = i4_0[_x]; I[1] = i4_1[_x];                   \
        I[2] = i4_2[_x]; I[3] = i4_3[_x];                   \
    } while (0)

    auto compute = [&](const float4 (&W)[JT], const float4 (&I)[BT]) {
        #pragma unroll
        for (int jj = 0; jj < JT; ++jj) {
            const float2 w01 = make_float2(W[jj].x, W[jj].y);
            const float2 w23 = make_float2(W[jj].z, W[jj].w);
            #pragma unroll
            for (int bi = 0; bi < BT; ++bi) {
                const float2 c2  = make_float2(cf[jj][bi], cf[jj][bi]);
                const float2 z01 = pk_mul(pk_mul(c2, w01), make_float2(I[bi].x, I[bi].y));
                const float2 z23 = pk_mul(pk_mul(c2, w23), make_float2(I[bi].z, I[bi].w));
                const float2 q2  = pk_fnma(z01, z23, pk_add(z01, z23));
                const float  q   = fmaf(-q2.x, q2.y, q2.x + q2.y);
                prod[jj][bi] = fma(-(double)q, prod[jj][bi], prod[jj][bi]);
            }
        }
    };

    // 8 stages (KH / 256 k per stage), A/B double buffer, dist-1 prefetch.
#define STEP(W, I, K)                                       \
    do {                                                    \
        compute(W, I);                                      \
        if ((K) + 2 < 8) LD(W, I, (K) + 2);                 \
    } while (0)

    LD(wA, iA, 0); LD(wB, iB, 1);
    STEP(wA, iA, 0); STEP(wB, iB, 1); STEP(wA, iA, 2); STEP(wB, iB, 3);
    STEP(wA, iA, 4); STEP(wB, iB, 5); STEP(wA, iA, 6); STEP(wB, iB, 7);
#undef STEP
#undef LD

    // 3 XOR-butterfly levels: every lane holds the partial over its mod-8
    // residue class for all 16 (jj,bi) values.
    #pragma unroll
    for (int off = 32; off >= 8; off >>= 1) {
        #pragma unroll
        for (int jj = 0; jj < JT; ++jj) {
            #pragma unroll
            for (int bi = 0; bi < BT; ++bi)
                prod[jj][bi] *= __shfl_xor(prod[jj][bi], off, 64);
        }
    }

    // 8-lane group g reduces values 2g and 2g+1 (jj = g>>1, bi = (g&1)*2 +{0,1}).
    const int g = lane >> 3;
    double v0 = prod[0][0], v1 = prod[0][1];
    v0 = (g == 1) ? prod[0][2] : v0;  v1 = (g == 1) ? prod[0][3] : v1;
    v0 = (g == 2) ? prod[1][0] : v0;  v1 = (g == 2) ? prod[1][1] : v1;
    v0 = (g == 3) ? prod[1][2] : v0;  v1 = (g == 3) ? prod[1][3] : v1;
    v0 = (g == 4) ? prod[2][0] : v0;  v1 = (g == 4) ? prod[2][1] : v1;
    v0 = (g == 5) ? prod[2][2] : v0;  v1 = (g == 5) ? prod[2][3] : v1;
    v0 = (g == 6) ? prod[3][0] : v0;  v1 = (g == 6) ? prod[3][1] : v1;
    v0 = (g == 7) ? prod[3][2] : v0;  v1 = (g == 7) ? prod[3][3] : v1;
    v0 *= __shfl_down(v0, 4, 64);  v1 *= __shfl_down(v1, 4, 64);
    v0 *= __shfl_down(v0, 2, 64);  v1 *= __shfl_down(v1, 2, 64);
    v0 *= __shfl_down(v0, 1, 64);  v1 *= __shfl_down(v1, 1, 64);

    if ((lane & 7) == 0) {
        const int jj  = g >> 1;
        const int bi0 = (g & 1) * 2;
        const int j   = j0 + jj;
        ws[((size_t)ks * BB + (b0 + bi0 + 0)) * NN + j] = v0;
        ws[((size_t)ks * BB + (b0 + bi0 + 1)) * NN + j] = v1;
    }
}

// Combine: tot = ws[0][b][j] * ws[1][b][j]; 4x4 mix + sampling epilogue.
// 32768 threads, fully coalesced over j.  (Verified in round 9.)
__global__ __launch_bounds__(256) void epi_combine(
    const float* __restrict__ state,    // [B,4,N]
    const float* __restrict__ psMatrix, // [4,4]
    const float* __restrict__ U,        // [N]
    const double* __restrict__ ws,      // [KS,BB,NN]
    float* __restrict__ out)            // [B,4,N]
{
    const int p = blockIdx.x * 256 + threadIdx.x;   // 0 .. BB*NN-1
    const int b = p >> 12;              // NN = 4096 = 2^12
    const int j = p & (NN - 1);

    const double tot = ws[(size_t)b * NN + j] * ws[((size_t)BB * NN) + (size_t)b * NN + j];
    const double ps1 = 1.0 - tot;

    // expand_psMatrix in f64
    double pm[4][4];
    #pragma unroll
    for (int r = 0; r < 4; ++r) {
        double s = 0.0;
        #pragma unroll
        for (int q = 0; q < 4; ++q) {
            pm[r][q] = (double)psMatrix[r * 4 + q];
            s += pm[r][q];
        }
        pm[r][r] += (1.0 - s);
    }

    double st[4];
    #pragma unroll
    for (int r = 0; r < 4; ++r)
        st[r] = (double)state[(size_t)b * 4 * NN + r * NN + j];

    const double S = st[0];
    const double ps10[4] = {1.0 - ps1, ps1, 0.0, 0.0};

    double P[4];
    #pragma unroll
    for (int i = 0; i < 4; ++i) {
        double acc = S * ps10[i];
        #pragma unroll
        for (int r = 1; r < 4; ++r)
            acc += pm[r][i] * st[r];
        P[i] = acc;
    }

    double u = (double)U[j];
    #pragma unroll
    for (int i = 0; i < 4; ++i) {
        u -= P[i];
        const double s = (u < 0.0) ? 1.0 : 0.0;
        out[(size_t)b * 4 * NN + i * NN + j] = (float)s;
        u += s;
    }
}

// ---------- Fallback (verbatim round-6 kernel, used only if ws too small) ----------
__global__ __launch_bounds__(256, 4) void epi_fallback(
    const float* __restrict__ state, const float* __restrict__ ISNet,
    const float* __restrict__ psMatrix, const float* __restrict__ U,
    float* __restrict__ out)
{
    const int j0 = blockIdx.x * JT;
    const int tid = threadIdx.x;
    const int wave = tid >> 6, lane = tid & 63;
    const int b0 = wave * 2;
    const float p01 = psMatrix[1];
    float cf[JT][2]; double prod[JT][2];
    #pragma unroll
    for (int jj = 0; jj < JT; ++jj)
        #pragma unroll
        for (int bi = 0; bi < 2; ++bi) {
            cf[jj][bi] = state[(size_t)(b0 + bi) * 4 * NN + (j0 + jj)] * p01;
            prod[jj][bi] = 1.0;
        }
    const float4* __restrict__ w0 = (const float4*)(ISNet + (size_t)(j0 + 0) * NN);
    const float4* __restrict__ w1 = (const float4*)(ISNet + (size_t)(j0 + 1) * NN);
    const float4* __restrict__ w2 = (const float4*)(ISNet + (size_t)(j0 + 2) * NN);
    const float4* __restrict__ w3 = (const float4*)(ISNet + (size_t)(j0 + 3) * NN);
    const float4* __restrict__ i0 = (const float4*)(state + ((size_t)(b0 + 0) * 4 + 2) * NN);
    const float4* __restrict__ i1 = (const float4*)(state + ((size_t)(b0 + 1) * 4 + 2) * NN);
    float4 wA[JT], wB[JT], wC[JT], ia[2], ib[2];
#define LW(BUF, IDX) do { const int _x = lane + (IDX) * 64; \
        BUF[0] = w0[_x]; BUF[1] = w1[_x]; BUF[2] = w2[_x]; BUF[3] = w3[_x]; } while (0)
#define LI(BUF, IDX) do { const int _x = lane + (IDX) * 64; \
        BUF[0] = i0[_x]; BUF[1] = i1[_x]; } while (0)
    auto compute = [&](const float4 (&W)[JT], const float4 (&I)[2]) {
        #pragma unroll
        for (int jj = 0; jj < JT; ++jj) {
            const float2 w01 = make_float2(W[jj].x, W[jj].y);
            const float2 w23 = make_float2(W[jj].z, W[jj].w);
            #pragma unroll
            for (int bi = 0; bi < 2; ++bi) {
                const float4& I4 = bi ? I[1] : I[0];
                const float2 c2 = make_float2(cf[jj][bi], cf[jj][bi]);
                const float2 z01 = pk_mul(pk_mul(c2, w01), make_float2(I4.x, I4.y));
                const float2 z23 = pk_mul(pk_mul(c2, w23), make_float2(I4.z, I4.w));
                const float2 q2 = pk_fnma(z01, z23, pk_add(z01, z23));
                const float q = fmaf(-q2.x, q2.y, q2.x + q2.y);
                prod[jj][bi] = fma(-(double)q, prod[jj][bi], prod[jj][bi]);
            }
        }
    };
#define STEP(W, I, K) do { compute(W, I); \
        if ((K) + 3 < 16) LW(W, (K) + 3); if ((K) + 2 < 16) LI(I, (K) + 2); } while (0)
    LW(wA, 0); LI(ia, 0); LW(wB, 1); LI(ib, 1); LW(wC, 2);
    STEP(wA, ia, 0);  STEP(wB, ib, 1);  STEP(wC, ia, 2);  STEP(wA, ib, 3);
    STEP(wB, ia, 4);  STEP(wC, ib, 5);  STEP(wA, ia, 6);  STEP(wB, ib, 7);
    STEP(wC, ia, 8);  STEP(wA, ib, 9);  STEP(wB, ia, 10); STEP(wC, ib, 11);
    STEP(wA, ia, 12); STEP(wB, ib, 13); STEP(wC, ia, 14); STEP(wA, ib, 15);
#undef STEP
#undef LW
#undef LI
    #pragma unroll
    for (int off = 32; off >= 8; off >>= 1)
        #pragma unroll
        for (int jj = 0; jj < JT; ++jj)
            #pragma unroll
            for (int bi = 0; bi < 2; ++bi)
                prod[jj][bi] *= __shfl_xor(prod[jj][bi], off, 64);
    const int g = lane >> 3;
    double v = prod[0][0];
    v = (g == 1) ? prod[0][1] : v; v = (g == 2) ? prod[1][0] : v;
    v = (g == 3) ? prod[1][1] : v; v = (g == 4) ? prod[2][0] : v;
    v = (g == 5) ? prod[2][1] : v; v = (g == 6) ? prod[3][0] : v;
    v = (g == 7) ? prod[3][1] : v;
    v *= __shfl_down(v, 4, 64); v *= __shfl_down(v, 2, 64); v *= __shfl_down(v, 1, 64);
    __shared__ double red[JT][BB];
    if ((lane & 7) == 0) red[g >> 1][b0 + (g & 1)] = v;
    __syncthreads();
    if (tid < JT * BB) {
        const int jj = tid >> 3, b = tid & 7;
        const int j = j0 + jj;
        const double ps1 = 1.0 - red[jj][b];
        double pm[4][4];
        #pragma unroll
        for (int r = 0; r < 4; ++r) {
            double s = 0.0;
            #pragma unroll
            for (int q = 0; q < 4; ++q) { pm[r][q] = (double)psMatrix[r * 4 + q]; s += pm[r][q]; }
            pm[r][r] += (1.0 - s);
        }
        double st[4];
        #pragma unroll
        for (int r = 0; r < 4; ++r) st[r] = (double)state[(size_t)b * 4 * NN + r * NN + j];
        const double S = st[0];
        const double ps10[4] = {1.0 - ps1, ps1, 0.0, 0.0};
        double P[4];
        #pragma unroll
        for (int i = 0; i < 4; ++i) {
            double acc = S * ps10[i];
            #pragma unroll
            for (int r = 1; r < 4; ++r) acc += pm[r][i] * st[r];
            P[i] = acc;
        }
        double u = (double)U[j];
        #pragma unroll
        for (int i = 0; i < 4; ++i) {
            u -= P[i];
            const double s = (u < 0.0) ? 1.0 : 0.0;
            out[(size_t)b * 4 * NN + i * NN + j] = (float)s;
            u += s;
        }
    }
}

extern "C" void kernel_launch(void* const* d_in, const int* in_sizes, int n_in,
                              void* d_out, int out_size, void* d_ws, size_t ws_size,
                              hipStream_t stream) {
    const float* state    = (const float*)d_in[0];  // [8,4,4096]
    const float* ISNet    = (const float*)d_in[1];  // [4096,4096]
    const float* psMatrix = (const float*)d_in[2];  // [4,4]
    const float* U        = (const float*)d_in[3];  // [4096]
    float* out            = (float*)d_out;          // [8,4,4096]

    const size_t need = (size_t)KS * BB * NN * sizeof(double);  // 512 KB
    if (ws_size >= need) {
        double* ws = (double*)d_ws;
        epi_partial<<<NN / JT, 256, 0, stream>>>(state, ISNet, psMatrix, ws);
        epi_combine<<<(BB * NN) / 256, 256, 0, stream>>>(state, psMatrix, U, ws, out);
    } else {
        epi_fallback<<<NN / JT, 256, 0, stream>>>(state, ISNet, psMatrix, U, out);
    }
}